// Round 4
// baseline (854.269 us; speedup 1.0000x reference)
//
#include <hip/hip_runtime.h>
#include <cstddef>

// Problem constants (fixed by the reference)
constexpr int NUM_ENT_C = 10000;
constexpr int SEQ_C     = 10;
constexpr int H_C       = 200;   // hidden dim
constexpr int OUT_C     = 100;   // word-embed / mid dim
constexpr int NG_C      = 2048;
constexpr int NREL_C    = 240;
constexpr int MQ_C      = 8;

typedef __attribute__((ext_vector_type(8))) short          bf16x8;
typedef __attribute__((ext_vector_type(4))) float          f32x4;
typedef __attribute__((ext_vector_type(8))) unsigned short u16x8;

__device__ __forceinline__ unsigned short f2bf(float v) {
    unsigned u = __float_as_uint(v);
    unsigned r = (u + 0x7FFFu + ((u >> 16) & 1u)) >> 16;   // RTN-even
    return (unsigned short)r;
}
__device__ __forceinline__ float bf2f(unsigned short b) {
    return __uint_as_float((unsigned)b << 16);
}

// ---------------------------------------------------------------------------
// f32 -> bf16 bulk convert (n multiple of 8)
// ---------------------------------------------------------------------------
__global__ void f2bf_arr_k(const float* __restrict__ src, unsigned short* __restrict__ dst,
                           size_t n8) {
    size_t stride = (size_t)gridDim.x * blockDim.x;
    for (size_t t = (size_t)blockIdx.x * blockDim.x + threadIdx.x; t < n8; t += stride) {
        const float* s = src + t * 8;
        u16x8 o;
        #pragma unroll
        for (int i = 0; i < 8; ++i) o[i] = f2bf(s[i]);
        *reinterpret_cast<u16x8*>(dst + t * 8) = o;
    }
}

// ---------------------------------------------------------------------------
// CSR build: histogram -> block scan -> bucket fill
// ---------------------------------------------------------------------------
__global__ void hist_k(const int* __restrict__ dIdx, int* __restrict__ deg, int E) {
    int stride = gridDim.x * blockDim.x;
    for (int t = blockIdx.x * blockDim.x + threadIdx.x; t < E; t += stride)
        atomicAdd(&deg[dIdx[t]], 1);
}

__global__ void scanA_k(const int* __restrict__ v, int* __restrict__ bsum, int n) {
    __shared__ int s[256];
    int t = threadIdx.x;
    int i = blockIdx.x * 256 + t;
    s[t] = (i < n) ? v[i] : 0;
    __syncthreads();
    for (int d = 128; d; d >>= 1) {
        if (t < d) s[t] += s[t + d];
        __syncthreads();
    }
    if (t == 0) bsum[blockIdx.x] = s[0];
}

__global__ void scanB_k(int* __restrict__ bsum, int nb) {
    __shared__ int s[256];
    int t = threadIdx.x;
    int v = (t < nb) ? bsum[t] : 0;
    s[t] = v;
    __syncthreads();
    for (int d = 1; d < 256; d <<= 1) {
        int x = (t >= d) ? s[t - d] : 0;
        __syncthreads();
        s[t] += x;
        __syncthreads();
    }
    if (t < nb) bsum[t] = s[t] - v;   // exclusive
}

__global__ void scanC_k(const int* __restrict__ v, const int* __restrict__ bsum,
                        int* __restrict__ offs, int* __restrict__ cur, int n) {
    __shared__ int s[256];
    int t = threadIdx.x;
    int i = blockIdx.x * 256 + t;
    int val = (i < n) ? v[i] : 0;
    s[t] = val;
    __syncthreads();
    for (int d = 1; d < 256; d <<= 1) {
        int x = (t >= d) ? s[t - d] : 0;
        __syncthreads();
        s[t] += x;
        __syncthreads();
    }
    if (i < n) {
        int ex = s[t] - val + bsum[blockIdx.x];
        offs[i] = ex;
        cur[i]  = ex;
    }
}

__global__ void fill_k(const int* __restrict__ dIdx, int* __restrict__ cur,
                       int* __restrict__ bkt, int E) {
    int stride = gridDim.x * blockDim.x;
    for (int t = blockIdx.x * blockDim.x + threadIdx.x; t < E; t += stride) {
        int d = dIdx[t];
        int p = atomicAdd(&cur[d], 1);
        bkt[p] = t;
    }
}

// ---------------------------------------------------------------------------
// Gather-mean (+ optional rel-subtract) + self-append + bf16 row write.
// One wave per destination node. Output row: [mean(K1) || self(K2) || 0-pad]
// SRCMODE: 0 direct, 1 word_id[src], 2 src % NUM_ENT. BF16IN: feat/self are bf16
// ---------------------------------------------------------------------------
template<int K1, int K2, int Kp, int SRCMODE, bool RELSUB, bool SELFMOD, bool BF16IN>
__global__ __launch_bounds__(256) void gather_mean_k(
        const void* __restrict__ featv, const void* __restrict__ selfv,
        const float* __restrict__ rel,
        const int* __restrict__ srcIdx, const int* __restrict__ typeIdx,
        const int* __restrict__ wordId,
        const int* __restrict__ offs, const int* __restrict__ deg,
        const int* __restrict__ bkt,
        unsigned short* __restrict__ dst, int n) {
    constexpr int NCH = (Kp + 63) / 64;
    int node = blockIdx.x * 4 + (threadIdx.x >> 6);
    int lane = threadIdx.x & 63;
    if (node >= n) return;
    float acc[NCH];
    #pragma unroll
    for (int c = 0; c < NCH; ++c) acc[c] = 0.f;
    int off = offs[node], dg = deg[node];
    for (int i = 0; i < dg; ++i) {
        int e = bkt[off + i];
        int s = srcIdx[e];
        if (SRCMODE == 1) s = wordId[s];
        if (SRCMODE == 2) s = s % NUM_ENT_C;
        const float* rr = RELSUB ? rel + (size_t)typeIdx[e] * K1 : nullptr;
        if (BF16IN) {
            const unsigned short* fr = (const unsigned short*)featv + (size_t)s * K1;
            #pragma unroll
            for (int c = 0; c < NCH; ++c) {
                int col = c * 64 + lane;
                if (col < K1) {
                    float v = bf2f(fr[col]);
                    if (RELSUB) v -= rr[col];
                    acc[c] += v;
                }
            }
        } else {
            const float* fr = (const float*)featv + (size_t)s * K1;
            #pragma unroll
            for (int c = 0; c < NCH; ++c) {
                int col = c * 64 + lane;
                if (col < K1) {
                    float v = fr[col];
                    if (RELSUB) v -= rr[col];
                    acc[c] += v;
                }
            }
        }
    }
    float inv = 1.f / fmaxf((float)dg, 1.f);
    int srow = SELFMOD ? (node % NUM_ENT_C) : node;
    unsigned short* drow = dst + (size_t)node * Kp;
    #pragma unroll
    for (int c = 0; c < NCH; ++c) {
        int col = c * 64 + lane;
        if (col >= Kp) continue;
        unsigned short ov;
        if (col < K1)           ov = f2bf(acc[c] * inv);
        else if (col < K1 + K2) {
            if (BF16IN) ov = ((const unsigned short*)selfv)[(size_t)srow * K2 + (col - K1)];
            else        ov = f2bf(((const float*)selfv)[(size_t)srow * K2 + (col - K1)]);
        } else ov = 0;
        drow[col] = ov;
    }
}

// ---------------------------------------------------------------------------
// Weight conversion: dst[n][k] bf16 = [W1(K1) ; W2(K2)] column n, zero-padded
// ---------------------------------------------------------------------------
__global__ void convW_k(const float* __restrict__ W1, int K1,
                        const float* __restrict__ W2, int K2, int N,
                        unsigned short* __restrict__ dst, int Nt, int Kp) {
    int total  = Nt * Kp;
    int stride = gridDim.x * blockDim.x;
    for (int t = blockIdx.x * blockDim.x + threadIdx.x; t < total; t += stride) {
        int n = t / Kp;
        int k = t - n * Kp;
        float v = 0.0f;
        if (n < N) {
            if (k < K1)           v = W1[(size_t)k * N + n];
            else if (k < K1 + K2) v = W2[(size_t)(k - K1) * N + n];
        }
        dst[t] = f2bf(v);
    }
}

// rows N..M of the final concat matrix: cols 200..400 = rel2[edge_type[r_ids[r]]]
__global__ void build_q_bf16_k(const float* __restrict__ rel2, const int* __restrict__ edge_type,
                               const int* __restrict__ r_ids, unsigned short* __restrict__ A,
                               int N, int M) {
    int R = M - N;
    size_t total  = (size_t)R * H_C;
    size_t stride = (size_t)gridDim.x * blockDim.x;
    for (size_t t = (size_t)blockIdx.x * blockDim.x + threadIdx.x; t < total; t += stride) {
        int r = (int)(t / H_C);
        int d = (int)(t - (size_t)r * H_C);
        int rr = r_ids[r];
        A[(size_t)(N + r) * 448 + 200 + d] = f2bf(rel2[(size_t)edge_type[rr] * H_C + d]);
    }
}

// zero cols [400,448) of every 448-wide row
__global__ void zero_pad_k(unsigned short* __restrict__ A, int M) {
    int total  = M * 6;
    int stride = gridDim.x * blockDim.x;
    for (int t = blockIdx.x * blockDim.x + threadIdx.x; t < total; t += stride) {
        int m = t / 6, c = t - m * 6;
        *reinterpret_cast<uint4*>(A + (size_t)m * 448 + 400 + c * 8) = make_uint4(0u, 0u, 0u, 0u);
    }
}

__global__ void rowoff_k(const int* __restrict__ node_slot, const int* __restrict__ edge_slot,
                         int* __restrict__ rowOff, int N, int M, int divq, int per, int embBase) {
    int stride = gridDim.x * blockDim.x;
    for (int m = blockIdx.x * blockDim.x + threadIdx.x; m < M; m += stride) {
        int off;
        if (m < N) {
            int ns = node_slot[m];
            int nid  = ns % NUM_ENT_C;
            int gidx = ns / divq;
            off = embBase + (nid * SEQ_C + gidx) * H_C;
        } else {
            int es  = edge_slot[m - N];
            int row = es / per;
            int pos = es - row * per;
            off = (row * SEQ_C + pos) * H_C;
        }
        rowOff[m] = off;
    }
}

// ---------------------------------------------------------------------------
// MFMA bf16 GEMM, 128-row blocks: C = act(A[M][Kp](lda) @ Wt[Nt][Kp]^T + bias)
// 4 waves; wave w owns rows {w*16..w*16+16} and {64+w*16..}; B-frag reused.
// OBF16: write bf16 at C[gm*ldc+gn]; else f32 (SCATTER: base=rowOff[gm])
// ---------------------------------------------------------------------------
template<int NF, int ACT, bool SCATTER, bool OBF16>
__global__ __launch_bounds__(256) void mfma_gemm_k(
        const unsigned short* __restrict__ A, int lda,
        const unsigned short* __restrict__ Wt,
        const float* __restrict__ bias, void* __restrict__ Cv, int ldc,
        const int* __restrict__ rowOff, int M, int N, int Kp) {
    constexpr int BN = NF * 16;
    __shared__ unsigned short As[128][40];
    __shared__ unsigned short Bs[BN][40];
    const int tid  = threadIdx.x;
    const int bm   = blockIdx.x * 128;
    const int w    = tid >> 6;
    const int lane = tid & 63;
    const int lr   = lane & 15;
    const int lk   = (lane >> 4) * 8;

    f32x4 acc0[NF], acc1[NF];
    #pragma unroll
    for (int nf = 0; nf < NF; ++nf) {
        acc0[nf] = (f32x4){0.f, 0.f, 0.f, 0.f};
        acc1[nf] = (f32x4){0.f, 0.f, 0.f, 0.f};
    }

    for (int k0 = 0; k0 < Kp; k0 += 32) {
        #pragma unroll
        for (int j = 0; j < 2; ++j) {   // stage A: 128 rows x 32k, 512 chunks
            int id = tid + j * 256;
            int m = id >> 2, c = id & 3;
            int gm = bm + m;
            uint4 v = make_uint4(0u, 0u, 0u, 0u);
            if (gm < M) v = *reinterpret_cast<const uint4*>(A + (size_t)gm * lda + k0 + c * 8);
            *reinterpret_cast<uint4*>(&As[m][c * 8]) = v;
        }
        for (int i = tid; i < NF * 64; i += 256) {   // stage B
            int n = i >> 2, c = i & 3;
            uint4 v = *reinterpret_cast<const uint4*>(Wt + (size_t)n * Kp + k0 + c * 8);
            *reinterpret_cast<uint4*>(&Bs[n][c * 8]) = v;
        }
        __syncthreads();
        bf16x8 a0 = *reinterpret_cast<const bf16x8*>(&As[w * 16 + lr][lk]);
        bf16x8 a1 = *reinterpret_cast<const bf16x8*>(&As[64 + w * 16 + lr][lk]);
        #pragma unroll
        for (int nf = 0; nf < NF; ++nf) {
            bf16x8 b = *reinterpret_cast<const bf16x8*>(&Bs[nf * 16 + lr][lk]);
            acc0[nf] = __builtin_amdgcn_mfma_f32_16x16x32_bf16(a0, b, acc0[nf], 0, 0, 0);
            acc1[nf] = __builtin_amdgcn_mfma_f32_16x16x32_bf16(a1, b, acc1[nf], 0, 0, 0);
        }
        __syncthreads();
    }

    const int r0 = (lane >> 4) * 4;
    #pragma unroll
    for (int h = 0; h < 2; ++h) {
        #pragma unroll
        for (int j = 0; j < 4; ++j) {
            int gm = bm + h * 64 + w * 16 + r0 + j;
            if (gm >= M) continue;
            size_t base;
            if (SCATTER && !OBF16) base = (size_t)rowOff[gm];
            else                   base = (size_t)gm * ldc;
            #pragma unroll
            for (int nf = 0; nf < NF; ++nf) {
                int gn = nf * 16 + lr;
                if (gn >= N) continue;
                float v = h ? acc1[nf][j] : acc0[nf][j];
                if (bias) v += bias[gn];
                if (ACT == 1) v = fmaxf(v, 0.f);
                if (ACT == 2) v = tanhf(v);
                if (OBF16) ((unsigned short*)Cv)[base + gn] = f2bf(v);
                else       ((float*)Cv)[base + gn] = v;
            }
        }
    }
}

template<int NF, int ACT, bool SCATTER, bool OBF16>
static void launch_mfma(hipStream_t s, const unsigned short* A, int lda,
                        const unsigned short* Wt, const float* bias,
                        void* C, int ldc, const int* rowOff, int M, int N, int Kp) {
    mfma_gemm_k<NF, ACT, SCATTER, OBF16><<<dim3((M + 127) / 128), 256, 0, s>>>(
        A, lda, Wt, bias, C, ldc, rowOff, M, N, Kp);
}

// ---------------------------------------------------------------------------
// Small f32 GEMM (240-row rel transforms)
// ---------------------------------------------------------------------------
__global__ __launch_bounds__(256) void gemm_f32_k(
        const float* __restrict__ A, const float* __restrict__ W,
        float* __restrict__ C, int M, int N, int K) {
    constexpr int TS = 64, BK = 16;
    __shared__ float As[BK][TS];
    __shared__ float Bs[BK][TS];
    int bm = blockIdx.x * TS, bn = blockIdx.y * TS;
    int tid = threadIdx.x;
    int tx = tid & 15, ty = tid >> 4;
    float acc[4][4] = {};
    for (int k0 = 0; k0 < K; k0 += BK) {
        #pragma unroll
        for (int l = tid; l < TS * BK; l += 256) {
            int m = l >> 4, kk = l & 15;
            int gm = bm + m, gk = k0 + kk;
            As[kk][m] = (gm < M && gk < K) ? A[(size_t)gm * K + gk] : 0.f;
        }
        #pragma unroll
        for (int l = tid; l < TS * BK; l += 256) {
            int kk = l >> 6, n = l & 63;
            int gk = k0 + kk, gn = bn + n;
            Bs[kk][n] = (gk < K && gn < N) ? W[(size_t)gk * N + gn] : 0.f;
        }
        __syncthreads();
        #pragma unroll
        for (int kk = 0; kk < BK; ++kk) {
            float a[4], b[4];
            #pragma unroll
            for (int i = 0; i < 4; ++i) a[i] = As[kk][ty * 4 + i];
            #pragma unroll
            for (int j = 0; j < 4; ++j) b[j] = Bs[kk][tx * 4 + j];
            #pragma unroll
            for (int i = 0; i < 4; ++i)
                #pragma unroll
                for (int j = 0; j < 4; ++j) acc[i][j] += a[i] * b[j];
        }
        __syncthreads();
    }
    #pragma unroll
    for (int i = 0; i < 4; ++i) {
        int gm = bm + ty * 4 + i;
        if (gm >= M) continue;
        #pragma unroll
        for (int j = 0; j < 4; ++j) {
            int gn = bn + tx * 4 + j;
            if (gn < N) C[(size_t)gm * N + gn] = acc[i][j];
        }
    }
}

// ---------------------------------------------------------------------------
// Attention: one wave per row; reads QA f32 + bf16 wh (rows reg-cached),
// writes ctx bf16 into concat matrix cols [0,200)
// ---------------------------------------------------------------------------
__global__ __launch_bounds__(256) void attn_k(
        const float* __restrict__ QA, const unsigned short* __restrict__ whb,
        const int* __restrict__ ent_idx, const int* __restrict__ ent_mask,
        const int* __restrict__ rel_idx, const int* __restrict__ rel_mask,
        unsigned short* __restrict__ ctxOut, int N, int M) {
    int wave = (int)(((size_t)blockIdx.x * blockDim.x + threadIdx.x) >> 6);
    int lane = threadIdx.x & 63;
    if (wave >= M) return;
    int m = wave;
    const int* idxp;
    const int* mskp;
    if (m < N) { idxp = ent_idx + (size_t)m * MQ_C;        mskp = ent_mask + (size_t)m * MQ_C; }
    else       { idxp = rel_idx + (size_t)(m - N) * MQ_C;  mskp = rel_mask + (size_t)(m - N) * MQ_C; }

    // each lane owns d = j*128 + lane*2 (+1); H_C=200 even
    float2 qa[2];
    #pragma unroll
    for (int j = 0; j < 2; ++j) {
        int d0 = j * 128 + lane * 2;
        qa[j] = (d0 < H_C) ? *reinterpret_cast<const float2*>(QA + (size_t)m * H_C + d0)
                           : make_float2(0.f, 0.f);
    }
    int   idx[MQ_C];
    float msk[MQ_C];
    float s[MQ_C];
    float2 wreg[MQ_C][2];
    #pragma unroll
    for (int k = 0; k < MQ_C; ++k) { idx[k] = idxp[k]; msk[k] = (float)mskp[k]; }
    #pragma unroll
    for (int k = 0; k < MQ_C; ++k) {
        const unsigned short* w = whb + (size_t)idx[k] * H_C;
        float p = 0.f;
        #pragma unroll
        for (int j = 0; j < 2; ++j) {
            int d0 = j * 128 + lane * 2;
            if (d0 < H_C) {
                unsigned u = *reinterpret_cast<const unsigned*>(w + d0);
                float lo = __uint_as_float(u << 16);
                float hi = __uint_as_float(u & 0xFFFF0000u);
                wreg[k][j] = make_float2(lo, hi);
                p += qa[j].x * lo + qa[j].y * hi;
            } else {
                wreg[k][j] = make_float2(0.f, 0.f);
            }
        }
        #pragma unroll
        for (int off = 32; off; off >>= 1) p += __shfl_xor(p, off);
        s[k] = p * msk[k];   // masked slot -> exact 0, matches reference
    }
    float mx = s[0];
    #pragma unroll
    for (int k = 1; k < MQ_C; ++k) mx = fmaxf(mx, s[k]);
    float den = 0.f;
    #pragma unroll
    for (int k = 0; k < MQ_C; ++k) { s[k] = expf(s[k] - mx); den += s[k]; }
    float inv = 1.f / den;
    #pragma unroll
    for (int j = 0; j < 2; ++j) {
        int d0 = j * 128 + lane * 2;
        if (d0 >= H_C) continue;
        float cx = 0.f, cy = 0.f;
        #pragma unroll
        for (int k = 0; k < MQ_C; ++k) {
            float a = s[k] * msk[k];
            cx += a * wreg[k][j].x;
            cy += a * wreg[k][j].y;
        }
        unsigned out = (unsigned)f2bf(cx * inv) | ((unsigned)f2bf(cy * inv) << 16);
        *reinterpret_cast<unsigned*>(ctxOut + (size_t)m * 448 + d0) = out;
    }
}

// ---------------------------------------------------------------------------

static inline dim3 ew_grid(size_t total) {
    size_t b = (total + 255) / 256;
    if (b > 4096) b = 4096;
    return dim3((unsigned)b);
}

extern "C" void kernel_launch(void* const* d_in, const int* in_sizes, int n_in,
                              void* d_out, int out_size, void* d_ws, size_t ws_size,
                              hipStream_t stream) {
    const float* ent_embeds = (const float*)d_in[0];
    const float* rel_embeds = (const float*)d_in[1];
    const float* word_embeds= (const float*)d_in[2];
    const float* gcn_w1     = (const float*)d_in[3];
    const float* gcn_b1     = (const float*)d_in[4];
    const float* gcn_w2     = (const float*)d_in[5];
    const float* gcn_b2     = (const float*)d_in[6];
    const float* cg1_wn     = (const float*)d_in[7];
    const float* cg1_wl     = (const float*)d_in[8];
    const float* cg1_wr     = (const float*)d_in[9];
    const float* cg2_wn     = (const float*)d_in[10];
    const float* cg2_wl     = (const float*)d_in[11];
    const float* cg2_wr     = (const float*)d_in[12];
    const float* attn_wa    = (const float*)d_in[13];
    const float* attn_wc    = (const float*)d_in[14];
    const int* node_slot    = (const int*)d_in[15];
    const int* edge_src     = (const int*)d_in[16];
    const int* edge_dst     = (const int*)d_in[17];
    const int* edge_type    = (const int*)d_in[18];
    const int* word_id      = (const int*)d_in[19];
    const int* wsrc         = (const int*)d_in[20];
    const int* wdst         = (const int*)d_in[21];
    const int* ent_word_idx = (const int*)d_in[22];
    const int* ent_word_mask= (const int*)d_in[23];
    const int* rel_word_idx = (const int*)d_in[24];
    const int* rel_word_mask= (const int*)d_in[25];
    const int* r_ids_graph  = (const int*)d_in[26];
    const int* edge_slot    = (const int*)d_in[27];

    const int N    = in_sizes[15];          // 50000
    const int E    = in_sizes[16];          // 200000
    const int Nw   = in_sizes[19];          // 30000
    const int Ew   = in_sizes[20];          // 300000
    const int Rsel = in_sizes[27];          // 8192
    const int M    = N + Rsel;              // 58192
    const int divq = N / SEQ_C;
    const int per  = Rsel / NG_C;
    const int embBase = NG_C * SEQ_C * H_C;
    const size_t entElems  = (size_t)in_sizes[0];   // 10000*200
    const size_t wembElems = (size_t)in_sizes[2];   // 40000*100

    // ---- workspace carving (float-indexed, 16B-aligned sub-buffers)
    float* ws = (float*)d_ws;
    size_t o = 0;
    auto align4 = [&]() { o = (o + 3) & ~(size_t)3; };
    int* wdeg  = (int*)(ws + o); o += Nw;
    int* woffs = (int*)(ws + o); o += Nw;
    int* wcur  = (int*)(ws + o); o += Nw;
    int* edeg  = (int*)(ws + o); o += N;
    int* eoffs = (int*)(ws + o); o += N;
    int* ecur  = (int*)(ws + o); o += N;
    int* wbkt  = (int*)(ws + o); o += Ew;
    int* ebkt  = (int*)(ws + o); o += E;
    int* bsum  = (int*)(ws + o); o += 256;
    int* rowOff= (int*)(ws + o); o += M;
    float* rel1 = ws + o; o += (size_t)NREL_C * OUT_C;
    float* rel2 = ws + o; o += (size_t)NREL_C * H_C;
    align4();
    unsigned short* Wt      = (unsigned short*)(ws + o); o += (208 * 448) / 2;
    align4();
    unsigned short* wh_bf   = (unsigned short*)(ws + o); o += ((size_t)Nw * H_C) / 2;     // word feats (persist)
    align4();
    unsigned short* h1_bf   = (unsigned short*)(ws + o); o += ((size_t)N * OUT_C) / 2;    // ent L1 out
    align4();
    unsigned short* ent_bf  = (unsigned short*)(ws + o); o += entElems / 2;
    align4();
    unsigned short* wemb_bf = (unsigned short*)(ws + o); o += wembElems / 2;
    align4();
    unsigned short* AbfF    = (unsigned short*)(ws + o); o += ((size_t)M * 448) / 2;      // [ctx||Q||pad]
    align4();
    float* BIG = ws + o;    // phase-local
    unsigned short* wh1_bf = (unsigned short*)BIG;                                  // word L1 out (Nw*200)
    unsigned short* AbfW   = (unsigned short*)(BIG + ((size_t)Nw * H_C) / 2);       // word A-mat (Nw*224)
    unsigned short* AbfE   = (unsigned short*)BIG;                                  // ent A-mat (N*416)
    float* QA = (float*)d_out;                                                      // M*200 f32 (dead before final memset)

    // =============== bf16 source tables + CSR build ===============
    f2bf_arr_k<<<ew_grid(entElems / 8), 256, 0, stream>>>(ent_embeds, ent_bf, entElems / 8);
    f2bf_arr_k<<<ew_grid(wembElems / 8), 256, 0, stream>>>(word_embeds, wemb_bf, wembElems / 8);
    hipMemsetAsync(wdeg, 0, (size_t)Nw * 4, stream);
    hipMemsetAsync(edeg, 0, (size_t)N * 4, stream);
    hist_k<<<ew_grid(Ew), 256, 0, stream>>>(wdst, wdeg, Ew);
    hist_k<<<ew_grid(E), 256, 0, stream>>>(edge_dst, edeg, E);
    {
        int nbW = (Nw + 255) / 256;
        scanA_k<<<nbW, 256, 0, stream>>>(wdeg, bsum, Nw);
        scanB_k<<<1, 256, 0, stream>>>(bsum, nbW);
        scanC_k<<<nbW, 256, 0, stream>>>(wdeg, bsum, woffs, wcur, Nw);
        fill_k<<<ew_grid(Ew), 256, 0, stream>>>(wdst, wcur, wbkt, Ew);
        int nbE = (N + 255) / 256;
        scanA_k<<<nbE, 256, 0, stream>>>(edeg, bsum, N);
        scanB_k<<<1, 256, 0, stream>>>(bsum, nbE);
        scanC_k<<<nbE, 256, 0, stream>>>(edeg, bsum, eoffs, ecur, N);
        fill_k<<<ew_grid(E), 256, 0, stream>>>(edge_dst, ecur, ebkt, E);
    }
    // rel chains (f32, tiny)
    gemm_f32_k<<<dim3((NREL_C + 63) / 64, (OUT_C + 63) / 64), 256, 0, stream>>>(
        rel_embeds, cg1_wr, rel1, NREL_C, OUT_C, H_C);
    gemm_f32_k<<<dim3((NREL_C + 63) / 64, (H_C + 63) / 64), 256, 0, stream>>>(
        rel1, cg2_wr, rel2, NREL_C, H_C, OUT_C);

    // =============== phase W: word GCN ===============
    // L1: A = mean(wemb_bf[word_id[wsrc]]) over wdst   [30000 x 128]
    gather_mean_k<OUT_C, 0, 128, 1, false, false, true><<<dim3((Nw + 3) / 4), 256, 0, stream>>>(
        wemb_bf, nullptr, nullptr, wsrc, nullptr, word_id, woffs, wdeg, wbkt, AbfW, Nw);
    convW_k<<<ew_grid(208 * 128), 256, 0, stream>>>(gcn_w1, OUT_C, nullptr, 0, H_C, Wt, 208, 128);
    launch_mfma<13, 1, false, true>(stream, AbfW, 128, Wt, gcn_b1, wh1_bf, H_C, nullptr, Nw, H_C, 128);
    // L2: A = mean(wh1_bf[wsrc]) over wdst   [30000 x 224]
    gather_mean_k<H_C, 0, 224, 0, false, false, true><<<dim3((Nw + 3) / 4), 256, 0, stream>>>(
        wh1_bf, nullptr, nullptr, wsrc, nullptr, nullptr, woffs, wdeg, wbkt, AbfW, Nw);
    convW_k<<<ew_grid(208 * 224), 256, 0, stream>>>(gcn_w2, H_C, nullptr, 0, H_C, Wt, 208, 224);
    launch_mfma<13, 1, false, true>(stream, AbfW, 224, Wt, gcn_b2, wh_bf, H_C, nullptr, Nw, H_C, 224);

    // =============== phase E: CompGCN ===============
    // L1: A = [mean(ent_bf[src%10k] - rel[type]) || ent_bf[n%10k]]   [50000 x 416]
    gather_mean_k<H_C, H_C, 416, 2, true, true, true><<<dim3((N + 3) / 4), 256, 0, stream>>>(
        ent_bf, ent_bf, rel_embeds, edge_src, edge_type, nullptr, eoffs, edeg, ebkt, AbfE, N);
    convW_k<<<ew_grid(112 * 416), 256, 0, stream>>>(cg1_wn, H_C, cg1_wl, H_C, OUT_C, Wt, 112, 416);
    launch_mfma<7, 1, false, true>(stream, AbfE, 416, Wt, nullptr, h1_bf, OUT_C, nullptr, N, OUT_C, 416);
    // L2: A = [mean(h1_bf[src] - rel1[type]) || h1_bf[n]]   [50000 x 224]
    gather_mean_k<OUT_C, OUT_C, 224, 0, true, false, true><<<dim3((N + 3) / 4), 256, 0, stream>>>(
        h1_bf, h1_bf, rel1, edge_src, edge_type, nullptr, eoffs, edeg, ebkt, AbfE, N);
    convW_k<<<ew_grid(208 * 224), 256, 0, stream>>>(cg2_wn, OUT_C, cg2_wl, OUT_C, H_C, Wt, 208, 224);
    // h2 -> bf16 directly into AbfF cols [200,400), rows [0,N)
    launch_mfma<13, 1, false, true>(stream, AbfE, 224, Wt, nullptr, AbfF + 200, 448, nullptr, N, H_C, 224);

    // =============== phase A: attention + output ===============
    build_q_bf16_k<<<ew_grid((size_t)Rsel * H_C), 256, 0, stream>>>(
        rel2, edge_type, r_ids_graph, AbfF, N, M);
    zero_pad_k<<<ew_grid((size_t)M * 6), 256, 0, stream>>>(AbfF, M);
    rowoff_k<<<ew_grid(M), 256, 0, stream>>>(node_slot, edge_slot, rowOff, N, M, divq, per, embBase);
    // QA = Q @ wa   (A = AbfF cols 200..424, lda=448), f32 out into d_out
    convW_k<<<ew_grid(208 * 224), 256, 0, stream>>>(attn_wa, H_C, nullptr, 0, H_C, Wt, 208, 224);
    launch_mfma<13, 0, false, false>(stream, AbfF + 200, 448, Wt, nullptr, QA, H_C, nullptr, M, H_C, 224);
    // attention -> ctx bf16 into AbfF cols [0,200)
    attn_k<<<(M + 3) / 4, 256, 0, stream>>>(QA, wh_bf, ent_word_idx, ent_word_mask,
                                            rel_word_idx, rel_word_mask, AbfF, N, M);
    // final: out = tanh([ctx||Q] @ wc) scattered into zeroed d_out
    hipMemsetAsync(d_out, 0, (size_t)out_size * 4, stream);
    convW_k<<<ew_grid(208 * 416), 256, 0, stream>>>(attn_wc, H_C, attn_wc + (size_t)H_C * H_C,
                                                    H_C, H_C, Wt, 208, 416);
    launch_mfma<13, 2, true, false>(stream, AbfF, 448, Wt, nullptr, d_out, H_C, rowOff, M, H_C, 416);
}

// Round 5
// 722.919 us; speedup vs baseline: 1.1817x; 1.1817x over previous
//
#include <hip/hip_runtime.h>
#include <cstddef>

constexpr int NUM_ENT_C = 10000;
constexpr int SEQ_C     = 10;
constexpr int H_C       = 200;
constexpr int OUT_C     = 100;
constexpr int NG_C      = 2048;
constexpr int NREL_C    = 240;
constexpr int MQ_C      = 8;

typedef __attribute__((ext_vector_type(8))) short          bf16x8;
typedef __attribute__((ext_vector_type(4))) float          f32x4;
typedef __attribute__((ext_vector_type(8))) unsigned short u16x8;

__device__ __forceinline__ unsigned short f2bf(float v) {
    unsigned u = __float_as_uint(v);
    unsigned r = (u + 0x7FFFu + ((u >> 16) & 1u)) >> 16;   // RTN-even
    return (unsigned short)r;
}
__device__ __forceinline__ float bf2f(unsigned short b) {
    return __uint_as_float((unsigned)b << 16);
}
// unpack uint (2 packed bf16) -> 2 floats
__device__ __forceinline__ void up2(unsigned u, float& lo, float& hi) {
    lo = __uint_as_float(u << 16);
    hi = __uint_as_float(u & 0xFFFF0000u);
}

// ---------------------------------------------------------------------------
// prep: bf16 tables + zero degree arrays
// ---------------------------------------------------------------------------
__global__ void prep_k(const float* __restrict__ ent, unsigned short* __restrict__ entb, size_t e8,
                       const float* __restrict__ wemb, unsigned short* __restrict__ wembb, size_t w8,
                       int* __restrict__ wdeg, int Nw, int* __restrict__ edeg, int N) {
    size_t total = e8 + w8 + (size_t)Nw + (size_t)N;
    size_t stride = (size_t)gridDim.x * blockDim.x;
    for (size_t t = (size_t)blockIdx.x * blockDim.x + threadIdx.x; t < total; t += stride) {
        if (t < e8) {
            const float* s = ent + t * 8;
            u16x8 o;
            #pragma unroll
            for (int i = 0; i < 8; ++i) o[i] = f2bf(s[i]);
            *reinterpret_cast<u16x8*>(entb + t * 8) = o;
        } else if (t < e8 + w8) {
            size_t tt = t - e8;
            const float* s = wemb + tt * 8;
            u16x8 o;
            #pragma unroll
            for (int i = 0; i < 8; ++i) o[i] = f2bf(s[i]);
            *reinterpret_cast<u16x8*>(wembb + tt * 8) = o;
        } else if (t < e8 + w8 + (size_t)Nw) {
            wdeg[t - e8 - w8] = 0;
        } else {
            edeg[t - e8 - w8 - Nw] = 0;
        }
    }
}

// ---------------------------------------------------------------------------
// CSR build
// ---------------------------------------------------------------------------
__global__ void hist2_k(const int* __restrict__ wdst, int Ew, int* __restrict__ wdeg,
                        const int* __restrict__ edst, int E, int* __restrict__ edeg) {
    int total = Ew + E;
    int stride = gridDim.x * blockDim.x;
    for (int t = blockIdx.x * blockDim.x + threadIdx.x; t < total; t += stride) {
        if (t < Ew) atomicAdd(&wdeg[wdst[t]], 1);
        else        atomicAdd(&edeg[edst[t - Ew]], 1);
    }
}

__global__ void scanA_k(const int* __restrict__ v, int* __restrict__ bsum, int n) {
    __shared__ int s[256];
    int t = threadIdx.x;
    int i = blockIdx.x * 256 + t;
    s[t] = (i < n) ? v[i] : 0;
    __syncthreads();
    for (int d = 128; d; d >>= 1) {
        if (t < d) s[t] += s[t + d];
        __syncthreads();
    }
    if (t == 0) bsum[blockIdx.x] = s[0];
}

__global__ void scanB_k(int* __restrict__ bsum, int nb) {
    __shared__ int s[256];
    int t = threadIdx.x;
    int v = (t < nb) ? bsum[t] : 0;
    s[t] = v;
    __syncthreads();
    for (int d = 1; d < 256; d <<= 1) {
        int x = (t >= d) ? s[t - d] : 0;
        __syncthreads();
        s[t] += x;
        __syncthreads();
    }
    if (t < nb) bsum[t] = s[t] - v;   // exclusive
}

__global__ void scanC_k(const int* __restrict__ v, const int* __restrict__ bsum,
                        int* __restrict__ offs, int* __restrict__ cur, int n) {
    __shared__ int s[256];
    int t = threadIdx.x;
    int i = blockIdx.x * 256 + t;
    int val = (i < n) ? v[i] : 0;
    s[t] = val;
    __syncthreads();
    for (int d = 1; d < 256; d <<= 1) {
        int x = (t >= d) ? s[t - d] : 0;
        __syncthreads();
        s[t] += x;
        __syncthreads();
    }
    if (i < n) {
        int ex = s[t] - val + bsum[blockIdx.x];
        offs[i] = ex;
        cur[i]  = ex;
    }
}

// fill with pre-resolved payloads
__global__ void fill2_k(const int* __restrict__ wdst, const int* __restrict__ wsrc,
                        const int* __restrict__ word_id, int Ew,
                        int* __restrict__ wcur, int* __restrict__ wbktA, int* __restrict__ wbktB,
                        const int* __restrict__ edst, const int* __restrict__ esrc,
                        const int* __restrict__ etype, int E,
                        int* __restrict__ ecur, int* __restrict__ ebktS, int* __restrict__ ebktT) {
    int total = Ew + E;
    int stride = gridDim.x * blockDim.x;
    for (int t = blockIdx.x * blockDim.x + threadIdx.x; t < total; t += stride) {
        if (t < Ew) {
            int ws = wsrc[t];
            int p = atomicAdd(&wcur[wdst[t]], 1);
            wbktA[p] = word_id[ws];
            wbktB[p] = ws;
        } else {
            int e = t - Ew;
            int p = atomicAdd(&ecur[edst[e]], 1);
            ebktS[p] = esrc[e];
            ebktT[p] = etype[e];
        }
    }
}

// ---------------------------------------------------------------------------
// Gather-mean (+ rel-subtract) + self-append, bf16 in/out, vectorized (4/lane)
// DUAL (K1==100): lane halves process 2 edges per iteration.
// ---------------------------------------------------------------------------
template<int K1, int K2, int Kp, bool RELSUB, bool SRCMOD, bool SELFMOD, bool DUAL>
__global__ __launch_bounds__(256) void gather_mean_k(
        const unsigned short* __restrict__ feat, const unsigned short* __restrict__ selfT,
        const float* __restrict__ rel,
        const int* __restrict__ bktS, const int* __restrict__ bktT,
        const int* __restrict__ offs, const int* __restrict__ deg,
        unsigned short* __restrict__ dst, int n) {
    int node = blockIdx.x * 4 + (threadIdx.x >> 6);
    int lane = threadIdx.x & 63;
    if (node >= n) return;
    int off = offs[node], dg = deg[node];
    float acc[4] = {0.f, 0.f, 0.f, 0.f};
    unsigned short* drow = dst + (size_t)node * Kp;

    if (DUAL) {
        int half = lane >> 5, lh = lane & 31;
        int d0 = lh * 4;
        bool act = d0 < K1;
        for (int i = 0; i < dg; i += 2) {
            int ii = i + half;
            if (ii < dg && act) {
                int s = bktS[off + ii];
                if (SRCMOD) s = s % NUM_ENT_C;
                uint2 u = *reinterpret_cast<const uint2*>(feat + (size_t)s * K1 + d0);
                float e0, e1, e2, e3;
                up2(u.x, e0, e1); up2(u.y, e2, e3);
                if (RELSUB) {
                    int tt = bktT[off + ii];
                    float4 rv = *reinterpret_cast<const float4*>(rel + (size_t)tt * K1 + d0);
                    e0 -= rv.x; e1 -= rv.y; e2 -= rv.z; e3 -= rv.w;
                }
                acc[0] += e0; acc[1] += e1; acc[2] += e2; acc[3] += e3;
            }
        }
        #pragma unroll
        for (int c = 0; c < 4; ++c) acc[c] += __shfl_xor(acc[c], 32);
        float inv = 1.f / fmaxf((float)dg, 1.f);
        if (half == 0 && act) {
            uint2 o;
            o.x = (unsigned)f2bf(acc[0] * inv) | ((unsigned)f2bf(acc[1] * inv) << 16);
            o.y = (unsigned)f2bf(acc[2] * inv) | ((unsigned)f2bf(acc[3] * inv) << 16);
            *reinterpret_cast<uint2*>(drow + d0) = o;
        }
        if (K2 > 0 && half == 1 && d0 < K2) {
            int srow = SELFMOD ? (node % NUM_ENT_C) : node;
            uint2 sv = *reinterpret_cast<const uint2*>(selfT + (size_t)srow * K2 + d0);
            *reinterpret_cast<uint2*>(drow + K1 + d0) = sv;
        }
    } else {
        int d0 = lane * 4;
        bool act = d0 < K1;
        for (int i = 0; i < dg; ++i) {
            if (act) {
                int s = bktS[off + i];
                if (SRCMOD) s = s % NUM_ENT_C;
                uint2 u = *reinterpret_cast<const uint2*>(feat + (size_t)s * K1 + d0);
                float e0, e1, e2, e3;
                up2(u.x, e0, e1); up2(u.y, e2, e3);
                if (RELSUB) {
                    int tt = bktT[off + i];
                    float4 rv = *reinterpret_cast<const float4*>(rel + (size_t)tt * K1 + d0);
                    e0 -= rv.x; e1 -= rv.y; e2 -= rv.z; e3 -= rv.w;
                }
                acc[0] += e0; acc[1] += e1; acc[2] += e2; acc[3] += e3;
            }
        }
        float inv = 1.f / fmaxf((float)dg, 1.f);
        if (act) {
            uint2 o;
            o.x = (unsigned)f2bf(acc[0] * inv) | ((unsigned)f2bf(acc[1] * inv) << 16);
            o.y = (unsigned)f2bf(acc[2] * inv) | ((unsigned)f2bf(acc[3] * inv) << 16);
            *reinterpret_cast<uint2*>(drow + d0) = o;
        }
        if (K2 > 0 && d0 < K2) {
            int srow = SELFMOD ? (node % NUM_ENT_C) : node;
            uint2 sv = *reinterpret_cast<const uint2*>(selfT + (size_t)srow * K2 + d0);
            *reinterpret_cast<uint2*>(drow + K1 + d0) = sv;
        }
    }
    for (int cc = K1 + K2 + lane; cc < Kp; cc += 64) drow[cc] = 0;
}

// ---------------------------------------------------------------------------
// All weight blocks -> one bf16 buffer (Wt layout [n][k], zero-padded)
// ---------------------------------------------------------------------------
__global__ void convw_all_k(const float* __restrict__ gcn_w1, const float* __restrict__ gcn_w2,
                            const float* __restrict__ cg1_wn, const float* __restrict__ cg1_wl,
                            const float* __restrict__ cg2_wn, const float* __restrict__ cg2_wl,
                            const float* __restrict__ attn_wa, const float* __restrict__ attn_wc,
                            unsigned short* __restrict__ Wt) {
    constexpr int S0 = 26624;            // gcn_w1  208x128 (K=100,N=200)
    constexpr int S1 = S0 + 46592;       // gcn_w2  208x224 (K=200,N=200)
    constexpr int S2 = S1 + 46592;       // cg1     112x416 (K=400,N=100)
    constexpr int S3 = S2 + 46592;       // cg2     208x224 (K=200,N=200)
    constexpr int S4 = S3 + 46592;       // wa      208x224 (K=200,N=200)
    constexpr int S5 = S4 + 86528;       // wc      208x416 (K=400,N=200)
    int stride = gridDim.x * blockDim.x;
    for (int t = blockIdx.x * blockDim.x + threadIdx.x; t < S5; t += stride) {
        float v = 0.f;
        if (t < S0) {
            int l = t, nn = l >> 7, k = l & 127;
            if (nn < 200 && k < 100) v = gcn_w1[k * 200 + nn];
        } else if (t < S1) {
            int l = t - S0, nn = l / 224, k = l - nn * 224;
            if (nn < 200 && k < 200) v = gcn_w2[k * 200 + nn];
        } else if (t < S2) {
            int l = t - S1, nn = l / 416, k = l - nn * 416;
            if (nn < 100) {
                if (k < 200)      v = cg1_wn[k * 100 + nn];
                else if (k < 400) v = cg1_wl[(k - 200) * 100 + nn];
            }
        } else if (t < S3) {
            int l = t - S2, nn = l / 224, k = l - nn * 224;
            if (nn < 200) {
                if (k < 100)      v = cg2_wn[k * 200 + nn];
                else if (k < 200) v = cg2_wl[(k - 100) * 200 + nn];
            }
        } else if (t < S4) {
            int l = t - S3, nn = l / 224, k = l - nn * 224;
            if (nn < 200 && k < 200) v = attn_wa[k * 200 + nn];
        } else {
            int l = t - S4, nn = l / 416, k = l - nn * 416;
            if (nn < 200 && k < 400) v = attn_wc[k * 200 + nn];
        }
        Wt[t] = f2bf(v);
    }
}

// ---------------------------------------------------------------------------
// post: build Q rows N..M (bf16), zero pad cols [400,448), rowOff map
// ---------------------------------------------------------------------------
__global__ void post_k(const float* __restrict__ rel2, const int* __restrict__ edge_type,
                       const int* __restrict__ r_ids, unsigned short* __restrict__ A,
                       const int* __restrict__ node_slot, const int* __restrict__ edge_slot,
                       int* __restrict__ rowOff, int N, int M, int divq, int per, int embBase) {
    int R = M - N;
    size_t secA = (size_t)R * H_C;
    size_t secB = secA + (size_t)M * 6;
    size_t total = secB + (size_t)M;
    size_t stride = (size_t)gridDim.x * blockDim.x;
    for (size_t t = (size_t)blockIdx.x * blockDim.x + threadIdx.x; t < total; t += stride) {
        if (t < secA) {
            int r = (int)(t / H_C);
            int d = (int)(t - (size_t)r * H_C);
            int rr = r_ids[r];
            A[(size_t)(N + r) * 448 + 200 + d] = f2bf(rel2[(size_t)edge_type[rr] * H_C + d]);
        } else if (t < secB) {
            size_t l = t - secA;
            int m = (int)(l / 6), c = (int)(l - (size_t)m * 6);
            *reinterpret_cast<uint4*>(A + (size_t)m * 448 + 400 + c * 8) = make_uint4(0u, 0u, 0u, 0u);
        } else {
            int m = (int)(t - secB);
            int offv;
            if (m < N) {
                int ns = node_slot[m];
                offv = embBase + ((ns % NUM_ENT_C) * SEQ_C + ns / divq) * H_C;
            } else {
                int es = edge_slot[m - N];
                offv = ((es / per) * SEQ_C + (es - (es / per) * per)) * H_C;
            }
            rowOff[m] = offv;
        }
    }
}

// ---------------------------------------------------------------------------
// MFMA bf16 GEMM, 128-row blocks
// ---------------------------------------------------------------------------
template<int NF, int ACT, bool SCATTER, bool OBF16>
__global__ __launch_bounds__(256) void mfma_gemm_k(
        const unsigned short* __restrict__ A, int lda,
        const unsigned short* __restrict__ Wt,
        const float* __restrict__ bias, void* __restrict__ Cv, int ldc,
        const int* __restrict__ rowOff, int M, int N, int Kp) {
    constexpr int BN = NF * 16;
    __shared__ unsigned short As[128][40];
    __shared__ unsigned short Bs[BN][40];
    const int tid  = threadIdx.x;
    const int bm   = blockIdx.x * 128;
    const int w    = tid >> 6;
    const int lane = tid & 63;
    const int lr   = lane & 15;
    const int lk   = (lane >> 4) * 8;

    f32x4 acc0[NF], acc1[NF];
    #pragma unroll
    for (int nf = 0; nf < NF; ++nf) {
        acc0[nf] = (f32x4){0.f, 0.f, 0.f, 0.f};
        acc1[nf] = (f32x4){0.f, 0.f, 0.f, 0.f};
    }

    for (int k0 = 0; k0 < Kp; k0 += 32) {
        #pragma unroll
        for (int j = 0; j < 2; ++j) {
            int id = tid + j * 256;
            int m = id >> 2, c = id & 3;
            int gm = bm + m;
            uint4 v = make_uint4(0u, 0u, 0u, 0u);
            if (gm < M) v = *reinterpret_cast<const uint4*>(A + (size_t)gm * lda + k0 + c * 8);
            *reinterpret_cast<uint4*>(&As[m][c * 8]) = v;
        }
        for (int i = tid; i < NF * 64; i += 256) {
            int n = i >> 2, c = i & 3;
            uint4 v = *reinterpret_cast<const uint4*>(Wt + (size_t)n * Kp + k0 + c * 8);
            *reinterpret_cast<uint4*>(&Bs[n][c * 8]) = v;
        }
        __syncthreads();
        bf16x8 a0 = *reinterpret_cast<const bf16x8*>(&As[w * 16 + lr][lk]);
        bf16x8 a1 = *reinterpret_cast<const bf16x8*>(&As[64 + w * 16 + lr][lk]);
        #pragma unroll
        for (int nf = 0; nf < NF; ++nf) {
            bf16x8 b = *reinterpret_cast<const bf16x8*>(&Bs[nf * 16 + lr][lk]);
            acc0[nf] = __builtin_amdgcn_mfma_f32_16x16x32_bf16(a0, b, acc0[nf], 0, 0, 0);
            acc1[nf] = __builtin_amdgcn_mfma_f32_16x16x32_bf16(a1, b, acc1[nf], 0, 0, 0);
        }
        __syncthreads();
    }

    const int r0 = (lane >> 4) * 4;
    #pragma unroll
    for (int h = 0; h < 2; ++h) {
        #pragma unroll
        for (int j = 0; j < 4; ++j) {
            int gm = bm + h * 64 + w * 16 + r0 + j;
            if (gm >= M) continue;
            size_t base;
            if (SCATTER && !OBF16) base = (size_t)rowOff[gm];
            else                   base = (size_t)gm * ldc;
            #pragma unroll
            for (int nf = 0; nf < NF; ++nf) {
                int gn = nf * 16 + lr;
                if (gn >= N) continue;
                float v = h ? acc1[nf][j] : acc0[nf][j];
                if (bias) v += bias[gn];
                if (ACT == 1) v = fmaxf(v, 0.f);
                if (ACT == 2) v = tanhf(v);
                if (OBF16) ((unsigned short*)Cv)[base + gn] = f2bf(v);
                else       ((float*)Cv)[base + gn] = v;
            }
        }
    }
}

template<int NF, int ACT, bool SCATTER, bool OBF16>
static void launch_mfma(hipStream_t s, const unsigned short* A, int lda,
                        const unsigned short* Wt, const float* bias,
                        void* C, int ldc, const int* rowOff, int M, int N, int Kp) {
    mfma_gemm_k<NF, ACT, SCATTER, OBF16><<<dim3((M + 127) / 128), 256, 0, s>>>(
        A, lda, Wt, bias, C, ldc, rowOff, M, N, Kp);
}

// ---------------------------------------------------------------------------
// Small f32 GEMM (240-row rel transforms)
// ---------------------------------------------------------------------------
__global__ __launch_bounds__(256) void gemm_f32_k(
        const float* __restrict__ A, const float* __restrict__ W,
        float* __restrict__ C, int M, int N, int K) {
    constexpr int TS = 64, BK = 16;
    __shared__ float As[BK][TS];
    __shared__ float Bs[BK][TS];
    int bm = blockIdx.x * TS, bn = blockIdx.y * TS;
    int tid = threadIdx.x;
    int tx = tid & 15, ty = tid >> 4;
    float acc[4][4] = {};
    for (int k0 = 0; k0 < K; k0 += BK) {
        #pragma unroll
        for (int l = tid; l < TS * BK; l += 256) {
            int m = l >> 4, kk = l & 15;
            int gm = bm + m, gk = k0 + kk;
            As[kk][m] = (gm < M && gk < K) ? A[(size_t)gm * K + gk] : 0.f;
        }
        #pragma unroll
        for (int l = tid; l < TS * BK; l += 256) {
            int kk = l >> 6, n = l & 63;
            int gk = k0 + kk, gn = bn + n;
            Bs[kk][n] = (gk < K && gn < N) ? W[(size_t)gk * N + gn] : 0.f;
        }
        __syncthreads();
        #pragma unroll
        for (int kk = 0; kk < BK; ++kk) {
            float a[4], b[4];
            #pragma unroll
            for (int i = 0; i < 4; ++i) a[i] = As[kk][ty * 4 + i];
            #pragma unroll
            for (int j = 0; j < 4; ++j) b[j] = Bs[kk][tx * 4 + j];
            #pragma unroll
            for (int i = 0; i < 4; ++i)
                #pragma unroll
                for (int j = 0; j < 4; ++j) acc[i][j] += a[i] * b[j];
        }
        __syncthreads();
    }
    #pragma unroll
    for (int i = 0; i < 4; ++i) {
        int gm = bm + ty * 4 + i;
        if (gm >= M) continue;
        #pragma unroll
        for (int j = 0; j < 4; ++j) {
            int gn = bn + tx * 4 + j;
            if (gn < N) C[(size_t)gm * N + gn] = acc[i][j];
        }
    }
}

// ---------------------------------------------------------------------------
// Attention: one wave/row; bf16 QA + bf16 wh, 4 elems/lane (uint2 per row),
// key rows cached packed in regs; ctx packed bf16 into concat matrix
// ---------------------------------------------------------------------------
__global__ __launch_bounds__(256) void attn_k(
        const unsigned short* __restrict__ QAb, const unsigned short* __restrict__ whb,
        const int* __restrict__ ent_idx, const int* __restrict__ ent_mask,
        const int* __restrict__ rel_idx, const int* __restrict__ rel_mask,
        unsigned short* __restrict__ ctxOut, int N, int M) {
    int m = blockIdx.x * 4 + (threadIdx.x >> 6);
    int lane = threadIdx.x & 63;
    if (m >= M) return;
    const int* idxp;
    const int* mskp;
    if (m < N) { idxp = ent_idx + (size_t)m * MQ_C;        mskp = ent_mask + (size_t)m * MQ_C; }
    else       { idxp = rel_idx + (size_t)(m - N) * MQ_C;  mskp = rel_mask + (size_t)(m - N) * MQ_C; }

    int d0 = lane * 4;
    bool act = d0 < H_C;   // lanes 0..49
    float qa0 = 0.f, qa1 = 0.f, qa2 = 0.f, qa3 = 0.f;
    if (act) {
        uint2 u = *reinterpret_cast<const uint2*>(QAb + (size_t)m * H_C + d0);
        up2(u.x, qa0, qa1); up2(u.y, qa2, qa3);
    }
    int   idx[MQ_C];
    float msk[MQ_C];
    float s[MQ_C];
    uint2 wr[MQ_C];
    #pragma unroll
    for (int k = 0; k < MQ_C; ++k) { idx[k] = idxp[k]; msk[k] = (float)mskp[k]; }
    #pragma unroll
    for (int k = 0; k < MQ_C; ++k) {
        float p = 0.f;
        if (act) {
            wr[k] = *reinterpret_cast<const uint2*>(whb + (size_t)idx[k] * H_C + d0);
            float e0, e1, e2, e3;
            up2(wr[k].x, e0, e1); up2(wr[k].y, e2, e3);
            p = qa0 * e0 + qa1 * e1 + qa2 * e2 + qa3 * e3;
        } else {
            wr[k] = make_uint2(0u, 0u);
        }
        #pragma unroll
        for (int off = 32; off; off >>= 1) p += __shfl_xor(p, off);
        s[k] = p * msk[k];   // masked slot -> exact 0, matches reference
    }
    float mx = s[0];
    #pragma unroll
    for (int k = 1; k < MQ_C; ++k) mx = fmaxf(mx, s[k]);
    float den = 0.f;
    #pragma unroll
    for (int k = 0; k < MQ_C; ++k) { s[k] = expf(s[k] - mx); den += s[k]; }
    float inv = 1.f / den;
    if (act) {
        float c0 = 0.f, c1 = 0.f, c2 = 0.f, c3 = 0.f;
        #pragma unroll
        for (int k = 0; k < MQ_C; ++k) {
            float a = s[k] * msk[k];
            float e0, e1, e2, e3;
            up2(wr[k].x, e0, e1); up2(wr[k].y, e2, e3);
            c0 += a * e0; c1 += a * e1; c2 += a * e2; c3 += a * e3;
        }
        uint2 o;
        o.x = (unsigned)f2bf(c0 * inv) | ((unsigned)f2bf(c1 * inv) << 16);
        o.y = (unsigned)f2bf(c2 * inv) | ((unsigned)f2bf(c3 * inv) << 16);
        *reinterpret_cast<uint2*>(ctxOut + (size_t)m * 448 + d0) = o;
    }
}

// ---------------------------------------------------------------------------

static inline dim3 ew_grid(size_t total) {
    size_t b = (total + 255) / 256;
    if (b > 4096) b = 4096;
    return dim3((unsigned)b);
}

extern "C" void kernel_launch(void* const* d_in, const int* in_sizes, int n_in,
                              void* d_out, int out_size, void* d_ws, size_t ws_size,
                              hipStream_t stream) {
    const float* ent_embeds = (const float*)d_in[0];
    const float* rel_embeds = (const float*)d_in[1];
    const float* word_embeds= (const float*)d_in[2];
    const float* gcn_w1     = (const float*)d_in[3];
    const float* gcn_b1     = (const float*)d_in[4];
    const float* gcn_w2     = (const float*)d_in[5];
    const float* gcn_b2     = (const float*)d_in[6];
    const float* cg1_wn     = (const float*)d_in[7];
    const float* cg1_wl     = (const float*)d_in[8];
    const float* cg1_wr     = (const float*)d_in[9];
    const float* cg2_wn     = (const float*)d_in[10];
    const float* cg2_wl     = (const float*)d_in[11];
    const float* cg2_wr     = (const float*)d_in[12];
    const float* attn_wa    = (const float*)d_in[13];
    const float* attn_wc    = (const float*)d_in[14];
    const int* node_slot    = (const int*)d_in[15];
    const int* edge_src     = (const int*)d_in[16];
    const int* edge_dst     = (const int*)d_in[17];
    const int* edge_type    = (const int*)d_in[18];
    const int* word_id      = (const int*)d_in[19];
    const int* wsrc         = (const int*)d_in[20];
    const int* wdst         = (const int*)d_in[21];
    const int* ent_word_idx = (const int*)d_in[22];
    const int* ent_word_mask= (const int*)d_in[23];
    const int* rel_word_idx = (const int*)d_in[24];
    const int* rel_word_mask= (const int*)d_in[25];
    const int* r_ids_graph  = (const int*)d_in[26];
    const int* edge_slot    = (const int*)d_in[27];

    const int N    = in_sizes[15];          // 50000
    const int E    = in_sizes[16];          // 200000
    const int Nw   = in_sizes[19];          // 30000
    const int Ew   = in_sizes[20];          // 300000
    const int Rsel = in_sizes[27];          // 8192
    const int M    = N + Rsel;              // 58192
    const int divq = N / SEQ_C;
    const int per  = Rsel / NG_C;
    const int embBase = NG_C * SEQ_C * H_C;
    const size_t entElems  = (size_t)in_sizes[0];   // 2,000,000
    const size_t wembElems = (size_t)in_sizes[2];   // 4,000,000

    // ---- workspace carving (float-indexed, 16B-aligned sub-buffers)
    float* ws = (float*)d_ws;
    size_t o = 0;
    auto align4 = [&]() { o = (o + 3) & ~(size_t)3; };
    int* wdeg  = (int*)(ws + o); o += Nw;
    int* woffs = (int*)(ws + o); o += Nw;
    int* wcur  = (int*)(ws + o); o += Nw;
    int* edeg  = (int*)(ws + o); o += N;
    int* eoffs = (int*)(ws + o); o += N;
    int* ecur  = (int*)(ws + o); o += N;
    int* wbktA = (int*)(ws + o); o += Ew;
    int* wbktB = (int*)(ws + o); o += Ew;
    int* ebktS = (int*)(ws + o); o += E;
    int* ebktT = (int*)(ws + o); o += E;
    int* bsum  = (int*)(ws + o); o += 256;
    int* rowOff= (int*)(ws + o); o += M;
    float* rel1 = ws + o; o += (size_t)NREL_C * OUT_C;
    float* rel2 = ws + o; o += (size_t)NREL_C * H_C;
    align4();
    unsigned short* Wt      = (unsigned short*)(ws + o); o += 299520 / 2;
    align4();
    unsigned short* wh_bf   = (unsigned short*)(ws + o); o += ((size_t)Nw * H_C) / 2;
    align4();
    unsigned short* h1_bf   = (unsigned short*)(ws + o); o += ((size_t)N * OUT_C) / 2;
    align4();
    unsigned short* ent_bf  = (unsigned short*)(ws + o); o += entElems / 2;
    align4();
    unsigned short* wemb_bf = (unsigned short*)(ws + o); o += wembElems / 2;
    align4();
    unsigned short* AbfF    = (unsigned short*)(ws + o); o += ((size_t)M * 448) / 2;  // [ctx||Q||pad]
    align4();
    float* BIG = ws + o;    // phase-local
    unsigned short* wh1_bf = (unsigned short*)BIG;                                  // Nw*200
    unsigned short* AbfW   = (unsigned short*)(BIG + ((size_t)Nw * H_C) / 2);       // Nw*224
    unsigned short* AbfE   = (unsigned short*)BIG;                                  // N*416
    unsigned short* QAb    = (unsigned short*)d_out;                                // M*200 bf16

    // Wt segment bases (elements)
    unsigned short* WT_g1 = Wt;                 // 208x128
    unsigned short* WT_g2 = Wt + 26624;         // 208x224
    unsigned short* WT_c1 = Wt + 73216;         // 112x416
    unsigned short* WT_c2 = Wt + 119808;        // 208x224
    unsigned short* WT_wa = Wt + 166400;        // 208x224
    unsigned short* WT_wc = Wt + 212992;        // 208x416

    // =============== prep + CSR build + weights ===============
    prep_k<<<ew_grid(entElems / 8 + wembElems / 8 + Nw + N), 256, 0, stream>>>(
        ent_embeds, ent_bf, entElems / 8, word_embeds, wemb_bf, wembElems / 8,
        wdeg, Nw, edeg, N);
    convw_all_k<<<ew_grid(299520), 256, 0, stream>>>(
        gcn_w1, gcn_w2, cg1_wn, cg1_wl, cg2_wn, cg2_wl, attn_wa, attn_wc, Wt);
    hist2_k<<<ew_grid((size_t)Ew + E), 256, 0, stream>>>(wdst, Ew, wdeg, edge_dst, E, edeg);
    {
        int nbW = (Nw + 255) / 256;
        scanA_k<<<nbW, 256, 0, stream>>>(wdeg, bsum, Nw);
        scanB_k<<<1, 256, 0, stream>>>(bsum, nbW);
        scanC_k<<<nbW, 256, 0, stream>>>(wdeg, bsum, woffs, wcur, Nw);
        int nbE = (N + 255) / 256;
        scanA_k<<<nbE, 256, 0, stream>>>(edeg, bsum, N);
        scanB_k<<<1, 256, 0, stream>>>(bsum, nbE);
        scanC_k<<<nbE, 256, 0, stream>>>(edeg, bsum, eoffs, ecur, N);
    }
    fill2_k<<<ew_grid((size_t)Ew + E), 256, 0, stream>>>(
        wdst, wsrc, word_id, Ew, wcur, wbktA, wbktB,
        edge_dst, edge_src, edge_type, E, ecur, ebktS, ebktT);
    // rel chains (f32, tiny)
    gemm_f32_k<<<dim3((NREL_C + 63) / 64, (OUT_C + 63) / 64), 256, 0, stream>>>(
        rel_embeds, cg1_wr, rel1, NREL_C, OUT_C, H_C);
    gemm_f32_k<<<dim3((NREL_C + 63) / 64, (H_C + 63) / 64), 256, 0, stream>>>(
        rel1, cg2_wr, rel2, NREL_C, H_C, OUT_C);
    post_k<<<ew_grid((size_t)Rsel * H_C + (size_t)M * 7), 256, 0, stream>>>(
        rel2, edge_type, r_ids_graph, AbfF, node_slot, edge_slot, rowOff,
        N, M, divq, per, embBase);

    // =============== phase W: word GCN ===============
    // L1: A = mean(wemb_bf[wid]) over wdst   [30000 x 128] (DUAL, K1=100)
    gather_mean_k<OUT_C, 0, 128, false, false, false, true><<<dim3((Nw + 3) / 4), 256, 0, stream>>>(
        wemb_bf, nullptr, nullptr, wbktA, nullptr, woffs, wdeg, AbfW, Nw);
    launch_mfma<13, 1, false, true>(stream, AbfW, 128, WT_g1, gcn_b1, wh1_bf, H_C, nullptr, Nw, H_C, 128);
    // L2: A = mean(wh1_bf[wsrc]) over wdst   [30000 x 224]
    gather_mean_k<H_C, 0, 224, false, false, false, false><<<dim3((Nw + 3) / 4), 256, 0, stream>>>(
        wh1_bf, nullptr, nullptr, wbktB, nullptr, woffs, wdeg, AbfW, Nw);
    launch_mfma<13, 1, false, true>(stream, AbfW, 224, WT_g2, gcn_b2, wh_bf, H_C, nullptr, Nw, H_C, 224);

    // =============== phase E: CompGCN ===============
    // L1: A = [mean(ent_bf[src%10k] - rel[type]) || ent_bf[n%10k]]   [50000 x 448->416K]
    gather_mean_k<H_C, H_C, 448, true, true, true, false><<<dim3((N + 3) / 4), 256, 0, stream>>>(
        ent_bf, ent_bf, rel_embeds, ebktS, ebktT, eoffs, edeg, AbfE, N);
    launch_mfma<7, 1, false, true>(stream, AbfE, 448, WT_c1, nullptr, h1_bf, OUT_C, nullptr, N, OUT_C, 416);
    // L2: A = [mean(h1_bf[src] - rel1[type]) || h1_bf[n]]   [50000 x 224] (DUAL, K1=100)
    gather_mean_k<OUT_C, OUT_C, 224, true, false, false, true><<<dim3((N + 3) / 4), 256, 0, stream>>>(
        h1_bf, h1_bf, rel1, ebktS, ebktT, eoffs, edeg, AbfE, N);
    // h2 -> bf16 directly into AbfF cols [200,400), rows [0,N)
    launch_mfma<13, 1, false, true>(stream, AbfE, 224, WT_c2, nullptr, AbfF + 200, 448, nullptr, N, H_C, 224);

    // =============== phase A: attention + output ===============
    // QA = Q @ wa  (A = AbfF cols 200..424, lda=448) -> bf16 in d_out
    launch_mfma<13, 0, false, true>(stream, AbfF + 200, 448, WT_wa, nullptr, QAb, H_C, nullptr, M, H_C, 224);
    attn_k<<<(M + 3) / 4, 256, 0, stream>>>(QAb, wh_bf, ent_word_idx, ent_word_mask,
                                            rel_word_idx, rel_word_mask, AbfF, N, M);
    // final: out = tanh([ctx||Q] @ wc) scattered into zeroed d_out
    hipMemsetAsync(d_out, 0, (size_t)out_size * 4, stream);
    launch_mfma<13, 2, true, false>(stream, AbfF, 448, WT_wc, nullptr, d_out, H_C, rowOff, M, H_C, 416);
}